// Round 1
// 387.843 us; speedup vs baseline: 1.0259x; 1.0259x over previous
//
#include <hip/hip_runtime.h>

typedef unsigned short u16;
typedef u16   u16x8  __attribute__((ext_vector_type(8)));
typedef __bf16 bf16x8 __attribute__((ext_vector_type(8)));
typedef float f32x4  __attribute__((ext_vector_type(4)));

constexpr int BATCH  = 4;
constexpr int CDIM   = 256;
constexpr int NTOK   = 16384;   // 128*128
constexpr int INNERD = 512;

__device__ __forceinline__ u16 f2b(float f) {
  union { float f; unsigned u; } v; v.f = f;
  return (u16)((v.u + 0x7fffu + ((v.u >> 16) & 1u)) >> 16);
}
__device__ __forceinline__ float b2f(u16 b) {
  union { unsigned u; float f; } v; v.u = ((unsigned)b) << 16;
  return v.f;
}

// async global->LDS, 16B per lane. LDS dest must be WAVE-UNIFORM base;
// HW writes lane i's data at base + i*16. Global src is per-lane.
__device__ __forceinline__ void async_ld16(const u16* g, u16* l) {
  __builtin_amdgcn_global_load_lds(
      (const __attribute__((address_space(1))) void*)g,
      (__attribute__((address_space(3))) void*)l, 16, 0, 0);
}

// ---------------- transpose + convert: (b,c,n) fp32 -> (b,n,c) bf16 -------------
__global__ __launch_bounds__(256) void transpose_cvt(
    const float* __restrict__ x, const float* __restrict__ ctx,
    u16* __restrict__ xt, u16* __restrict__ ct) {
  __shared__ float tile[64][33];
  int zb = blockIdx.z;            // 0..7 : b*2 + which
  int b = zb >> 1;
  const float* src = (zb & 1) ? ctx : x;
  u16* dst = (zb & 1) ? ct : xt;
  src += (size_t)b * CDIM * NTOK;
  dst += (size_t)b * NTOK * CDIM;
  int n0 = blockIdx.x * 32, c0 = blockIdx.y * 64;
  int tx = threadIdx.x & 31, ty = threadIdx.x >> 5;   // ty 0..7
#pragma unroll
  for (int i = 0; i < 64; i += 8)
    tile[ty + i][tx] = src[(size_t)(c0 + ty + i) * NTOK + n0 + tx];
  __syncthreads();
  int nl = threadIdx.x >> 3;          // 0..31
  int cl = (threadIdx.x & 7) * 8;     // 0..56
  u16x8 o;
#pragma unroll
  for (int j = 0; j < 8; j++) o[j] = f2b(tile[cl + j][nl]);
  *(u16x8*)&dst[(size_t)(n0 + nl) * CDIM + c0 + cl] = o;
}

// ---------------- weight transpose: (256,512) fp32 -> (512,256) bf16 ------------
__global__ __launch_bounds__(256) void wtrans(
    const float* __restrict__ Wq, const float* __restrict__ Wk, const float* __restrict__ Wv,
    u16* __restrict__ qt, u16* __restrict__ kt, u16* __restrict__ vt) {
  __shared__ float tile[32][33];
  const float* src = blockIdx.z == 0 ? Wq : (blockIdx.z == 1 ? Wk : Wv);
  u16* dst = blockIdx.z == 0 ? qt : (blockIdx.z == 1 ? kt : vt);
  int i0 = blockIdx.x * 32, c0 = blockIdx.y * 32;
  int tx = threadIdx.x & 31, ty = threadIdx.x >> 5;
#pragma unroll
  for (int r = 0; r < 32; r += 8)
    tile[ty + r][tx] = src[(size_t)(c0 + ty + r) * INNERD + i0 + tx];
  __syncthreads();
#pragma unroll
  for (int r = 0; r < 32; r += 8)
    dst[(size_t)(i0 + ty + r) * CDIM + c0 + tx] = f2b(tile[tx][ty + r]);
}

// ---------------- projection GEMM (m97 staging: global_load_lds + linear LDS) ---
// K-half: ktb[b][i][n] = exp(sum_c Wk[c][i]*ctx[b][c][n])
// V-half: vtb[b][i][n] =      sum_c Wv[c][i]*ctx[b][c][n]
#define MT 128
#define NT 128
#define KB 64

__global__ __launch_bounds__(256) void proj_gemm(
    const u16* __restrict__ Wkt, const u16* __restrict__ Wvt,
    const u16* __restrict__ ctx_bt, u16* __restrict__ ktp, u16* __restrict__ vtp) {
  // flattened grid 4096 = 4(x) * 128(y) * 8(z); chunked XCD swizzle:
  // each XCD gets 512 consecutive swz ids = exactly one z stream, with the
  // 4 x-siblings (sharing each B tile) adjacent in time on the same L2.
  int id = blockIdx.x;
  int swz = (id & 7) * 512 + (id >> 3);
  int bx = swz & 3, by = (swz >> 2) & 127, z = swz >> 9;
  int b = z >> 1;
  bool isK = !(z & 1);
  const u16* A  = isK ? Wkt : Wvt;
  const u16* Bt = ctx_bt + (size_t)b * NTOK * CDIM;
  u16* Out = (isK ? ktp : vtp) + (size_t)b * INNERD * NTOK;
  int i0 = bx * MT;
  int n0 = by * NT;

  __shared__ __align__(16) u16 As[MT * KB];   // linear [128][64], 16 KiB
  __shared__ __align__(16) u16 Bs[NT * KB];   // linear [128][64], 16 KiB

  int tid = threadIdx.x;
  int wave = tid >> 6, lane = tid & 63;
  int wm = (wave >> 1) * 64, wn = (wave & 1) * 64;
  int quad = lane >> 4, l16 = lane & 15;

  // staging geometry: issue t covers 8 rows x 64 cols = 1 KiB;
  // lane covers row t*8+(lane>>3), u16 col (lane&7)*8
  int srow = lane >> 3, scol = (lane & 7) * 8;

  f32x4 acc[4][4];
#pragma unroll
  for (int i = 0; i < 4; i++)
#pragma unroll
    for (int j = 0; j < 4; j++) acc[i][j] = (f32x4)(0.0f);

  for (int k0 = 0; k0 < CDIM; k0 += KB) {
    __syncthreads();                      // prev-iter reads done before overwrite
#pragma unroll
    for (int j = 0; j < 4; j++) {
      int t = wave * 4 + j;               // 0..15
      int row = t * 8 + srow;
      async_ld16(&A [(size_t)(i0 + row) * CDIM + k0 + scol], &As[t * 512]);
      async_ld16(&Bt[(size_t)(n0 + row) * CDIM + k0 + scol], &Bs[t * 512]);
    }
    __syncthreads();                      // compiler drains vmcnt(0) before barrier
#pragma unroll
    for (int kk = 0; kk < KB; kk += 32) {
      int ko = kk + quad * 8;
      bf16x8 af[4], bfr[4];
#pragma unroll
      for (int m = 0; m < 4; m++)
        af[m] = __builtin_bit_cast(bf16x8, *(const u16x8*)&As[(wm + m * 16 + l16) * KB + ko]);
#pragma unroll
      for (int e = 0; e < 4; e++)
        bfr[e] = __builtin_bit_cast(bf16x8, *(const u16x8*)&Bs[(wn + e * 16 + l16) * KB + ko]);
#pragma unroll
      for (int m = 0; m < 4; m++)
#pragma unroll
        for (int e = 0; e < 4; e++)
          acc[m][e] = __builtin_amdgcn_mfma_f32_16x16x32_bf16(af[m], bfr[e], acc[m][e], 0, 0, 0);
    }
  }
#pragma unroll
  for (int m = 0; m < 4; m++) {
    int rowb = i0 + wm + m * 16 + quad * 4;
#pragma unroll
    for (int e = 0; e < 4; e++) {
      int col = n0 + wn + e * 16 + l16;
#pragma unroll
      for (int r = 0; r < 4; r++) {
        float v = acc[m][e][r];
        if (isK) v = __expf(v);          // block-uniform branch
        Out[(size_t)(rowb + r) * NTOK + col] = f2b(v);
      }
    }
  }
}

// ---------------- zero scratch -------------------------------------------------
__global__ void zero_f32(float* p, int nelem) {
  int i = blockIdx.x * blockDim.x + threadIdx.x;
  if (i < nelem) p[i] = 0.0f;
}

// ------- cm[b,h][d][e] = sum_n expk[d][n] * v[e][n]; ksum[b][h*64+d] = sum_n expk
#define CM_CHUNK 2048
__global__ __launch_bounds__(256) void ctx_mat(
    const u16* __restrict__ ktp, const u16* __restrict__ vtp,
    float* __restrict__ cm, float* __restrict__ ksum) {
  int bh = blockIdx.x;            // 0..31
  int b = bh >> 3, h = bh & 7;
  const u16* Ak = ktp + ((size_t)b * INNERD + h * 64) * NTOK;
  const u16* Av = vtp + ((size_t)b * INNERD + h * 64) * NTOK;
  int tid = threadIdx.x, wave = tid >> 6, lane = tid & 63;
  int quad = lane >> 4, l16 = lane & 15;
  size_t nb = (size_t)blockIdx.y * CM_CHUNK + wave * (CM_CHUNK / 4);

  u16x8 ov;
#pragma unroll
  for (int t = 0; t < 8; t++) ov[t] = 0x3f80;      // bf16 1.0
  const bf16x8 ones = __builtin_bit_cast(bf16x8, ov);

  f32x4 acc[4][4];
  f32x4 accS[4];
#pragma unroll
  for (int i = 0; i < 4; i++) {
    accS[i] = (f32x4)(0.0f);
#pragma unroll
    for (int j = 0; j < 4; j++) acc[i][j] = (f32x4)(0.0f);
  }

  for (int n = 0; n < CM_CHUNK / 4; n += 32) {
    size_t col = nb + n + quad * 8;
    bf16x8 a[4], vv[4];
#pragma unroll
    for (int m = 0; m < 4; m++)
      a[m] = __builtin_bit_cast(bf16x8, *(const u16x8*)&Ak[(size_t)(m * 16 + l16) * NTOK + col]);
#pragma unroll
    for (int e = 0; e < 4; e++)
      vv[e] = __builtin_bit_cast(bf16x8, *(const u16x8*)&Av[(size_t)(e * 16 + l16) * NTOK + col]);
#pragma unroll
    for (int m = 0; m < 4; m++) {
      accS[m] = __builtin_amdgcn_mfma_f32_16x16x32_bf16(a[m], ones, accS[m], 0, 0, 0);
#pragma unroll
      for (int e = 0; e < 4; e++)
        acc[m][e] = __builtin_amdgcn_mfma_f32_16x16x32_bf16(a[m], vv[e], acc[m][e], 0, 0, 0);
    }
  }

  __shared__ float red[64 * 64];
  __shared__ float redS[64];
  for (int w = 0; w < 4; w++) {
    if (wave == w) {
#pragma unroll
      for (int m = 0; m < 4; m++)
#pragma unroll
        for (int e = 0; e < 4; e++)
#pragma unroll
          for (int r = 0; r < 4; r++) {
            int d = m * 16 + quad * 4 + r, ee = e * 16 + l16;
            if (w == 0) red[d * 64 + ee] = acc[m][e][r];
            else        red[d * 64 + ee] += acc[m][e][r];
          }
      if (l16 == 0) {
#pragma unroll
        for (int m = 0; m < 4; m++)
#pragma unroll
          for (int r = 0; r < 4; r++) {
            int d = m * 16 + quad * 4 + r;
            if (w == 0) redS[d] = accS[m][r];
            else        redS[d] += accS[m][r];
          }
      }
    }
    __syncthreads();
  }
  float* cmp = cm + (size_t)bh * 64 * 64;
#pragma unroll
  for (int j = tid; j < 4096; j += 256) atomicAdd(&cmp[j], red[j]);
  if (tid < 64) atomicAdd(&ksum[(size_t)b * INNERD + h * 64 + tid], redS[tid]);
}

// ---------------- weff[b][i=h*64+d][c] = (sum_e cm[d][e]*Wo[h*64+e][c])/ksum ---
__global__ __launch_bounds__(256) void weff_k(
    const float* __restrict__ cm, const float* __restrict__ Wo,
    const float* __restrict__ ksum, float* __restrict__ weff) {
  int bi = blockIdx.x;            // 0..2047
  int b = bi >> 9, i = bi & 511, h = i >> 6, d = i & 63;
  const float* cmr = cm + ((size_t)(b * 8 + h) * 64 + d) * 64;
  __shared__ float cs[64];
  if (threadIdx.x < 64) cs[threadIdx.x] = cmr[threadIdx.x];
  __syncthreads();
  float inv = 1.0f / ksum[(size_t)b * INNERD + i];
  int c = threadIdx.x;
  float s = 0.0f;
#pragma unroll 8
  for (int e = 0; e < 64; e++) s += cs[e] * Wo[(size_t)(h * 64 + e) * CDIM + c];
  weff[(size_t)bi * CDIM + c] = s * inv;
}

// ---------------- Gt[b][c][c'] = sum_i weff[b][i][c] * Wq_t[i][c']  (bf16) -----
__global__ __launch_bounds__(256) void gt_k(
    const float* __restrict__ weff, const u16* __restrict__ Wq_t, u16* __restrict__ Gt) {
  int bc = blockIdx.x;            // 0..1023
  int b = bc >> 8, c = bc & 255;
  __shared__ float ws[512];
  for (int j = threadIdx.x; j < 512; j += 256)
    ws[j] = weff[((size_t)b * 512 + j) * CDIM + c];
  __syncthreads();
  int cp = threadIdx.x;
  float s = 0.0f;
#pragma unroll 8
  for (int i = 0; i < 512; i++) s += ws[i] * b2f(Wq_t[(size_t)i * CDIM + cp]);
  Gt[(size_t)bc * CDIM + cp] = f2b(s);
}

// ---------------- final: out[b][c][n] = x + bo[c] + sum_c' Gt[c][c'] x_bt[n][c']
__global__ __launch_bounds__(256) void final_gemm(
    const u16* __restrict__ Gt, const u16* __restrict__ x_bt,
    const float* __restrict__ x, const float* __restrict__ bo,
    float* __restrict__ out) {
  // flattened grid 1024 = 2(x) * 128(y) * 4(z); chunked XCD swizzle
  int id = blockIdx.x;
  int swz = (id & 7) * 128 + (id >> 3);
  int bx = swz & 1, by = (swz >> 1) & 127, b = swz >> 8;
  const u16* A  = Gt + (size_t)b * CDIM * CDIM;
  const u16* Bt = x_bt + (size_t)b * NTOK * CDIM;
  const float* xb = x + (size_t)b * CDIM * NTOK;
  float* ob = out + (size_t)b * CDIM * NTOK;
  int i0 = bx * MT;       // 0 or 128
  int n0 = by * NT;

  __shared__ __align__(16) u16 As[MT * KB];
  __shared__ __align__(16) u16 Bs[NT * KB];

  int tid = threadIdx.x;
  int wave = tid >> 6, lane = tid & 63;
  int wm = (wave >> 1) * 64, wn = (wave & 1) * 64;
  int quad = lane >> 4, l16 = lane & 15;
  int srow = lane >> 3, scol = (lane & 7) * 8;

  f32x4 acc[4][4];
#pragma unroll
  for (int i = 0; i < 4; i++)
#pragma unroll
    for (int j = 0; j < 4; j++) acc[i][j] = (f32x4)(0.0f);

  for (int k0 = 0; k0 < CDIM; k0 += KB) {
    __syncthreads();
#pragma unroll
    for (int j = 0; j < 4; j++) {
      int t = wave * 4 + j;
      int row = t * 8 + srow;
      async_ld16(&A [(size_t)(i0 + row) * CDIM + k0 + scol], &As[t * 512]);
      async_ld16(&Bt[(size_t)(n0 + row) * CDIM + k0 + scol], &Bs[t * 512]);
    }
    __syncthreads();
#pragma unroll
    for (int kk = 0; kk < KB; kk += 32) {
      int ko = kk + quad * 8;
      bf16x8 af[4], bfr[4];
#pragma unroll
      for (int m = 0; m < 4; m++)
        af[m] = __builtin_bit_cast(bf16x8, *(const u16x8*)&As[(wm + m * 16 + l16) * KB + ko]);
#pragma unroll
      for (int e = 0; e < 4; e++)
        bfr[e] = __builtin_bit_cast(bf16x8, *(const u16x8*)&Bs[(wn + e * 16 + l16) * KB + ko]);
#pragma unroll
      for (int m = 0; m < 4; m++)
#pragma unroll
        for (int e = 0; e < 4; e++)
          acc[m][e] = __builtin_amdgcn_mfma_f32_16x16x32_bf16(af[m], bfr[e], acc[m][e], 0, 0, 0);
    }
  }
#pragma unroll
  for (int m = 0; m < 4; m++) {
    int rowb = i0 + wm + m * 16 + quad * 4;
#pragma unroll
    for (int e = 0; e < 4; e++) {
      int col = n0 + wn + e * 16 + l16;
#pragma unroll
      for (int r = 0; r < 4; r++) {
        int c = rowb + r;
        ob[(size_t)c * NTOK + col] = acc[m][e][r] + xb[(size_t)c * NTOK + col] + bo[c];
      }
    }
  }
}

extern "C" void kernel_launch(void* const* d_in, const int* in_sizes, int n_in,
                              void* d_out, int out_size, void* d_ws, size_t ws_size,
                              hipStream_t stream) {
  const float* x   = (const float*)d_in[0];
  const float* ctx = (const float*)d_in[1];
  const float* Wq  = (const float*)d_in[2];
  const float* Wk  = (const float*)d_in[3];
  const float* Wv  = (const float*)d_in[4];
  const float* Wo  = (const float*)d_in[5];
  const float* bo  = (const float*)d_in[6];
  float* out = (float*)d_out;

  char* ws = (char*)d_ws;
  u16* ctx_bt = (u16*)ws;  ws += (size_t)BATCH * NTOK * CDIM * 2;     // 32 MiB
  u16* x_bt   = (u16*)ws;  ws += (size_t)BATCH * NTOK * CDIM * 2;     // 32 MiB
  u16* Wq_t   = (u16*)ws;  ws += (size_t)INNERD * CDIM * 2;
  u16* Wk_t   = (u16*)ws;  ws += (size_t)INNERD * CDIM * 2;
  u16* Wv_t   = (u16*)ws;  ws += (size_t)INNERD * CDIM * 2;
  u16* ktb    = (u16*)ws;  ws += (size_t)BATCH * INNERD * NTOK * 2;   // 64 MiB (holds exp(k))
  u16* vtb    = (u16*)ws;  ws += (size_t)BATCH * INNERD * NTOK * 2;   // 64 MiB
  float* cm   = (float*)ws; ws += (size_t)BATCH * 8 * 64 * 64 * 4;    // 512 KiB
  float* ksum = (float*)ws; ws += (size_t)BATCH * INNERD * 4;         // 8 KiB (contiguous after cm)
  float* weff = (float*)ws; ws += (size_t)BATCH * INNERD * CDIM * 4;  // 2 MiB
  u16* Gt     = (u16*)ws;  ws += (size_t)BATCH * CDIM * CDIM * 2;

  const int nzero = BATCH * 8 * 64 * 64 + BATCH * INNERD;  // cm + ksum

  transpose_cvt<<<dim3(NTOK / 32, CDIM / 64, BATCH * 2), 256, 0, stream>>>(x, ctx, x_bt, ctx_bt);
  wtrans<<<dim3(INNERD / 32, CDIM / 32, 3), 256, 0, stream>>>(Wq, Wk, Wv, Wq_t, Wk_t, Wv_t);
  zero_f32<<<(nzero + 255) / 256, 256, 0, stream>>>(cm, nzero);
  proj_gemm<<<dim3(4096), 256, 0, stream>>>(Wk_t, Wv_t, ctx_bt, ktb, vtb);
  ctx_mat<<<dim3(BATCH * 8, NTOK / CM_CHUNK), 256, 0, stream>>>(ktb, vtb, cm, ksum);
  weff_k<<<BATCH * INNERD, 256, 0, stream>>>(cm, Wo, ksum, weff);
  gt_k<<<BATCH * CDIM, 256, 0, stream>>>(weff, Wq_t, Gt);
  final_gemm<<<dim3(1024), 256, 0, stream>>>(Gt, x_bt, x, bo, out);
}

// Round 2
// 370.205 us; speedup vs baseline: 1.0747x; 1.0476x over previous
//
#include <hip/hip_runtime.h>

typedef unsigned short u16;
typedef u16   u16x4  __attribute__((ext_vector_type(4)));
typedef u16   u16x8  __attribute__((ext_vector_type(8)));
typedef __bf16 bf16x8 __attribute__((ext_vector_type(8)));
typedef float f32x4  __attribute__((ext_vector_type(4)));

constexpr int BATCH  = 4;
constexpr int CDIM   = 256;
constexpr int NTOK   = 16384;   // 128*128
constexpr int INNERD = 512;

__device__ __forceinline__ u16 f2b(float f) {
  union { float f; unsigned u; } v; v.f = f;
  return (u16)((v.u + 0x7fffu + ((v.u >> 16) & 1u)) >> 16);
}
__device__ __forceinline__ float b2f(u16 b) {
  union { unsigned u; float f; } v; v.u = ((unsigned)b) << 16;
  return v.f;
}

// async global->LDS, 16B per lane. LDS dest must be WAVE-UNIFORM base;
// HW writes lane i's data at base + i*16. Global src is per-lane.
__device__ __forceinline__ void async_ld16(const u16* g, u16* l) {
  __builtin_amdgcn_global_load_lds(
      (const __attribute__((address_space(1))) void*)g,
      (__attribute__((address_space(3))) void*)l, 16, 0, 0);
}

// ---------------- transpose + convert: (b,c,n) fp32 -> (b,n,c) bf16 -------------
__global__ __launch_bounds__(256) void transpose_cvt(
    const float* __restrict__ x, const float* __restrict__ ctx,
    u16* __restrict__ xt, u16* __restrict__ ct) {
  __shared__ float tile[64][33];
  int zb = blockIdx.z;            // 0..7 : b*2 + which
  int b = zb >> 1;
  const float* src = (zb & 1) ? ctx : x;
  u16* dst = (zb & 1) ? ct : xt;
  src += (size_t)b * CDIM * NTOK;
  dst += (size_t)b * NTOK * CDIM;
  int n0 = blockIdx.x * 32, c0 = blockIdx.y * 64;
  int tx = threadIdx.x & 31, ty = threadIdx.x >> 5;   // ty 0..7
#pragma unroll
  for (int i = 0; i < 64; i += 8)
    tile[ty + i][tx] = src[(size_t)(c0 + ty + i) * NTOK + n0 + tx];
  __syncthreads();
  int nl = threadIdx.x >> 3;          // 0..31
  int cl = (threadIdx.x & 7) * 8;     // 0..56
  u16x8 o;
#pragma unroll
  for (int j = 0; j < 8; j++) o[j] = f2b(tile[cl + j][nl]);
  *(u16x8*)&dst[(size_t)(n0 + nl) * CDIM + c0 + cl] = o;
}

// ---------------- weight transpose: (256,512) fp32 -> (512,256) bf16 ------------
__global__ __launch_bounds__(256) void wtrans(
    const float* __restrict__ Wq, const float* __restrict__ Wk, const float* __restrict__ Wv,
    u16* __restrict__ qt, u16* __restrict__ kt, u16* __restrict__ vt) {
  __shared__ float tile[32][33];
  const float* src = blockIdx.z == 0 ? Wq : (blockIdx.z == 1 ? Wk : Wv);
  u16* dst = blockIdx.z == 0 ? qt : (blockIdx.z == 1 ? kt : vt);
  int i0 = blockIdx.x * 32, c0 = blockIdx.y * 32;
  int tx = threadIdx.x & 31, ty = threadIdx.x >> 5;
#pragma unroll
  for (int r = 0; r < 32; r += 8)
    tile[ty + r][tx] = src[(size_t)(c0 + ty + r) * INNERD + i0 + tx];
  __syncthreads();
#pragma unroll
  for (int r = 0; r < 32; r += 8)
    dst[(size_t)(i0 + ty + r) * CDIM + c0 + tx] = f2b(tile[tx][ty + r]);
}

// ---------------- projection GEMM (m97 staging; SWAPPED operands so each lane ---
// holds 4 consecutive n in its acc regs -> 8B vectorized stores) ----------------
// K-half: ktb[b][i][n] = exp(sum_c Wk[c][i]*ctx[b][c][n])
// V-half: vtb[b][i][n] =      sum_c Wv[c][i]*ctx[b][c][n]
#define MT 128
#define NT 128
#define KB 64

__global__ __launch_bounds__(256) void proj_gemm(
    const u16* __restrict__ Wkt, const u16* __restrict__ Wvt,
    const u16* __restrict__ ctx_bt, u16* __restrict__ ktp, u16* __restrict__ vtp) {
  // flattened grid 4096 = 4(x) * 128(y) * 8(z); chunked XCD swizzle
  int id = blockIdx.x;
  int swz = (id & 7) * 512 + (id >> 3);
  int bx = swz & 3, by = (swz >> 2) & 127, z = swz >> 9;
  int b = z >> 1;
  bool isK = !(z & 1);
  const u16* A  = isK ? Wkt : Wvt;
  const u16* Bt = ctx_bt + (size_t)b * NTOK * CDIM;
  u16* Out = (isK ? ktp : vtp) + (size_t)b * INNERD * NTOK;
  int i0 = bx * MT;
  int n0 = by * NT;

  __shared__ __align__(16) u16 As[MT * KB];   // linear [128][64], 16 KiB
  __shared__ __align__(16) u16 Bs[NT * KB];   // linear [128][64], 16 KiB

  int tid = threadIdx.x;
  int wave = tid >> 6, lane = tid & 63;
  int wm = (wave >> 1) * 64, wn = (wave & 1) * 64;
  int quad = lane >> 4, l16 = lane & 15;
  int srow = lane >> 3, scol = (lane & 7) * 8;

  // acc[e][m]: rows of output-transposed tile = n (from B-operand-as-A),
  //            cols = i (from A-operand-as-B)
  f32x4 acc[4][4];
#pragma unroll
  for (int i = 0; i < 4; i++)
#pragma unroll
    for (int j = 0; j < 4; j++) acc[i][j] = (f32x4)(0.0f);

  for (int k0 = 0; k0 < CDIM; k0 += KB) {
    __syncthreads();                      // prev-iter reads done before overwrite
#pragma unroll
    for (int j = 0; j < 4; j++) {
      int t = wave * 4 + j;               // 0..15
      int row = t * 8 + srow;
      async_ld16(&A [(size_t)(i0 + row) * CDIM + k0 + scol], &As[t * 512]);
      async_ld16(&Bt[(size_t)(n0 + row) * CDIM + k0 + scol], &Bs[t * 512]);
    }
    __syncthreads();                      // drains vmcnt(0) before barrier
#pragma unroll
    for (int kk = 0; kk < KB; kk += 32) {
      int ko = kk + quad * 8;
      bf16x8 af[4], bfr[4];
#pragma unroll
      for (int m = 0; m < 4; m++)
        af[m] = __builtin_bit_cast(bf16x8, *(const u16x8*)&As[(wm + m * 16 + l16) * KB + ko]);
#pragma unroll
      for (int e = 0; e < 4; e++)
        bfr[e] = __builtin_bit_cast(bf16x8, *(const u16x8*)&Bs[(wn + e * 16 + l16) * KB + ko]);
#pragma unroll
      for (int e = 0; e < 4; e++)
#pragma unroll
        for (int m = 0; m < 4; m++)
          acc[e][m] = __builtin_amdgcn_mfma_f32_16x16x32_bf16(bfr[e], af[m], acc[e][m], 0, 0, 0);
    }
  }
  // lane's acc[e][m][r] maps to i = i0+wm+m*16+l16, n = n0+wn+e*16+quad*4+r
#pragma unroll
  for (int e = 0; e < 4; e++) {
    int nb = n0 + wn + e * 16 + quad * 4;
#pragma unroll
    for (int m = 0; m < 4; m++) {
      int irow = i0 + wm + m * 16 + l16;
      u16x4 o;
#pragma unroll
      for (int r = 0; r < 4; r++) {
        float v = acc[e][m][r];
        if (isK) v = __expf(v);          // block-uniform branch
        o[r] = f2b(v);
      }
      *(u16x4*)&Out[(size_t)irow * NTOK + nb] = o;
    }
  }
}

// ---------------- zero scratch -------------------------------------------------
__global__ void zero_f32(float* p, int nelem) {
  int i = blockIdx.x * blockDim.x + threadIdx.x;
  if (i < nelem) p[i] = 0.0f;
}

// ------- cm[b,h][d][e] = sum_n expk[d][n] * v[e][n]; ksum[b][h*64+d] = sum_n expk
#define CM_CHUNK 2048
__global__ __launch_bounds__(256) void ctx_mat(
    const u16* __restrict__ ktp, const u16* __restrict__ vtp,
    float* __restrict__ cm, float* __restrict__ ksum) {
  int bh = blockIdx.x;            // 0..31
  int b = bh >> 3, h = bh & 7;
  const u16* Ak = ktp + ((size_t)b * INNERD + h * 64) * NTOK;
  const u16* Av = vtp + ((size_t)b * INNERD + h * 64) * NTOK;
  int tid = threadIdx.x, wave = tid >> 6, lane = tid & 63;
  int quad = lane >> 4, l16 = lane & 15;
  size_t nb = (size_t)blockIdx.y * CM_CHUNK + wave * (CM_CHUNK / 4);

  u16x8 ov;
#pragma unroll
  for (int t = 0; t < 8; t++) ov[t] = 0x3f80;      // bf16 1.0
  const bf16x8 ones = __builtin_bit_cast(bf16x8, ov);

  f32x4 acc[4][4];
  f32x4 accS[4];
#pragma unroll
  for (int i = 0; i < 4; i++) {
    accS[i] = (f32x4)(0.0f);
#pragma unroll
    for (int j = 0; j < 4; j++) acc[i][j] = (f32x4)(0.0f);
  }

  for (int n = 0; n < CM_CHUNK / 4; n += 32) {
    size_t col = nb + n + quad * 8;
    bf16x8 a[4], vv[4];
#pragma unroll
    for (int m = 0; m < 4; m++)
      a[m] = __builtin_bit_cast(bf16x8, *(const u16x8*)&Ak[(size_t)(m * 16 + l16) * NTOK + col]);
#pragma unroll
    for (int e = 0; e < 4; e++)
      vv[e] = __builtin_bit_cast(bf16x8, *(const u16x8*)&Av[(size_t)(e * 16 + l16) * NTOK + col]);
#pragma unroll
    for (int m = 0; m < 4; m++) {
      accS[m] = __builtin_amdgcn_mfma_f32_16x16x32_bf16(a[m], ones, accS[m], 0, 0, 0);
#pragma unroll
      for (int e = 0; e < 4; e++)
        acc[m][e] = __builtin_amdgcn_mfma_f32_16x16x32_bf16(a[m], vv[e], acc[m][e], 0, 0, 0);
    }
  }

  __shared__ float red[64 * 64];
  __shared__ float redS[64];
  for (int w = 0; w < 4; w++) {
    if (wave == w) {
#pragma unroll
      for (int m = 0; m < 4; m++)
#pragma unroll
        for (int e = 0; e < 4; e++)
#pragma unroll
          for (int r = 0; r < 4; r++) {
            int d = m * 16 + quad * 4 + r, ee = e * 16 + l16;
            if (w == 0) red[d * 64 + ee] = acc[m][e][r];
            else        red[d * 64 + ee] += acc[m][e][r];
          }
      if (l16 == 0) {
#pragma unroll
        for (int m = 0; m < 4; m++)
#pragma unroll
          for (int r = 0; r < 4; r++) {
            int d = m * 16 + quad * 4 + r;
            if (w == 0) redS[d] = accS[m][r];
            else        redS[d] += accS[m][r];
          }
      }
    }
    __syncthreads();
  }
  float* cmp = cm + (size_t)bh * 64 * 64;
#pragma unroll
  for (int j = tid; j < 4096; j += 256) atomicAdd(&cmp[j], red[j]);
  if (tid < 64) atomicAdd(&ksum[(size_t)b * INNERD + h * 64 + tid], redS[tid]);
}

// ---------------- weff[b][i=h*64+d][c] = (sum_e cm[d][e]*Wo[h*64+e][c])/ksum ---
__global__ __launch_bounds__(256) void weff_k(
    const float* __restrict__ cm, const float* __restrict__ Wo,
    const float* __restrict__ ksum, float* __restrict__ weff) {
  int bi = blockIdx.x;            // 0..2047
  int b = bi >> 9, i = bi & 511, h = i >> 6, d = i & 63;
  const float* cmr = cm + ((size_t)(b * 8 + h) * 64 + d) * 64;
  __shared__ float cs[64];
  if (threadIdx.x < 64) cs[threadIdx.x] = cmr[threadIdx.x];
  __syncthreads();
  float inv = 1.0f / ksum[(size_t)b * INNERD + i];
  int c = threadIdx.x;
  float s = 0.0f;
#pragma unroll 8
  for (int e = 0; e < 64; e++) s += cs[e] * Wo[(size_t)(h * 64 + e) * CDIM + c];
  weff[(size_t)bi * CDIM + c] = s * inv;
}

// ---------------- Gt[b][c][c'] = sum_i weff[b][i][c] * Wq_t[i][c']  (bf16) -----
__global__ __launch_bounds__(256) void gt_k(
    const float* __restrict__ weff, const u16* __restrict__ Wq_t, u16* __restrict__ Gt) {
  int bc = blockIdx.x;            // 0..1023
  int b = bc >> 8, c = bc & 255;
  __shared__ float ws[512];
  for (int j = threadIdx.x; j < 512; j += 256)
    ws[j] = weff[((size_t)b * 512 + j) * CDIM + c];
  __syncthreads();
  int cp = threadIdx.x;
  float s = 0.0f;
#pragma unroll 8
  for (int i = 0; i < 512; i++) s += ws[i] * b2f(Wq_t[(size_t)i * CDIM + cp]);
  Gt[(size_t)bc * CDIM + cp] = f2b(s);
}

// ---------------- final: out[b][c][n] = x + bo[c] + sum_c' Gt[c][c'] x_bt[n][c']
// SWAPPED operands: lane holds 4 consecutive n -> float4 load of x, float4 store.
__global__ __launch_bounds__(256) void final_gemm(
    const u16* __restrict__ Gt, const u16* __restrict__ x_bt,
    const float* __restrict__ x, const float* __restrict__ bo,
    float* __restrict__ out) {
  // flattened grid 1024 = 2(x) * 128(y) * 4(z); chunked XCD swizzle
  int id = blockIdx.x;
  int swz = (id & 7) * 128 + (id >> 3);
  int bx = swz & 1, by = (swz >> 1) & 127, b = swz >> 8;
  const u16* A  = Gt + (size_t)b * CDIM * CDIM;
  const u16* Bt = x_bt + (size_t)b * NTOK * CDIM;
  const float* xb = x + (size_t)b * CDIM * NTOK;
  float* ob = out + (size_t)b * CDIM * NTOK;
  int i0 = bx * MT;       // 0 or 128
  int n0 = by * NT;

  __shared__ __align__(16) u16 As[MT * KB];
  __shared__ __align__(16) u16 Bs[NT * KB];

  int tid = threadIdx.x;
  int wave = tid >> 6, lane = tid & 63;
  int wm = (wave >> 1) * 64, wn = (wave & 1) * 64;
  int quad = lane >> 4, l16 = lane & 15;
  int srow = lane >> 3, scol = (lane & 7) * 8;

  f32x4 acc[4][4];   // [e:n-frag][m:c-frag]
#pragma unroll
  for (int i = 0; i < 4; i++)
#pragma unroll
    for (int j = 0; j < 4; j++) acc[i][j] = (f32x4)(0.0f);

  for (int k0 = 0; k0 < CDIM; k0 += KB) {
    __syncthreads();
#pragma unroll
    for (int j = 0; j < 4; j++) {
      int t = wave * 4 + j;
      int row = t * 8 + srow;
      async_ld16(&A [(size_t)(i0 + row) * CDIM + k0 + scol], &As[t * 512]);
      async_ld16(&Bt[(size_t)(n0 + row) * CDIM + k0 + scol], &Bs[t * 512]);
    }
    __syncthreads();
#pragma unroll
    for (int kk = 0; kk < KB; kk += 32) {
      int ko = kk + quad * 8;
      bf16x8 af[4], bfr[4];
#pragma unroll
      for (int m = 0; m < 4; m++)
        af[m] = __builtin_bit_cast(bf16x8, *(const u16x8*)&As[(wm + m * 16 + l16) * KB + ko]);
#pragma unroll
      for (int e = 0; e < 4; e++)
        bfr[e] = __builtin_bit_cast(bf16x8, *(const u16x8*)&Bs[(wn + e * 16 + l16) * KB + ko]);
#pragma unroll
      for (int e = 0; e < 4; e++)
#pragma unroll
        for (int m = 0; m < 4; m++)
          acc[e][m] = __builtin_amdgcn_mfma_f32_16x16x32_bf16(bfr[e], af[m], acc[e][m], 0, 0, 0);
    }
  }
  // lane's acc[e][m][r]: c = i0+wm+m*16+l16, n = n0+wn+e*16+quad*4+r
#pragma unroll
  for (int e = 0; e < 4; e++) {
    int nb = n0 + wn + e * 16 + quad * 4;
#pragma unroll
    for (int m = 0; m < 4; m++) {
      int c = i0 + wm + m * 16 + l16;
      f32x4 xv = *(const f32x4*)&xb[(size_t)c * NTOK + nb];
      f32x4 r;
      float bc = bo[c];
#pragma unroll
      for (int t = 0; t < 4; t++) r[t] = acc[e][m][t] + xv[t] + bc;
      *(f32x4*)&ob[(size_t)c * NTOK + nb] = r;
    }
  }
}

extern "C" void kernel_launch(void* const* d_in, const int* in_sizes, int n_in,
                              void* d_out, int out_size, void* d_ws, size_t ws_size,
                              hipStream_t stream) {
  const float* x   = (const float*)d_in[0];
  const float* ctx = (const float*)d_in[1];
  const float* Wq  = (const float*)d_in[2];
  const float* Wk  = (const float*)d_in[3];
  const float* Wv  = (const float*)d_in[4];
  const float* Wo  = (const float*)d_in[5];
  const float* bo  = (const float*)d_in[6];
  float* out = (float*)d_out;

  char* ws = (char*)d_ws;
  u16* ctx_bt = (u16*)ws;  ws += (size_t)BATCH * NTOK * CDIM * 2;     // 32 MiB
  u16* x_bt   = (u16*)ws;  ws += (size_t)BATCH * NTOK * CDIM * 2;     // 32 MiB
  u16* Wq_t   = (u16*)ws;  ws += (size_t)INNERD * CDIM * 2;
  u16* Wk_t   = (u16*)ws;  ws += (size_t)INNERD * CDIM * 2;
  u16* Wv_t   = (u16*)ws;  ws += (size_t)INNERD * CDIM * 2;
  u16* ktb    = (u16*)ws;  ws += (size_t)BATCH * INNERD * NTOK * 2;   // 64 MiB (holds exp(k))
  u16* vtb    = (u16*)ws;  ws += (size_t)BATCH * INNERD * NTOK * 2;   // 64 MiB
  float* cm   = (float*)ws; ws += (size_t)BATCH * 8 * 64 * 64 * 4;    // 512 KiB
  float* ksum = (float*)ws; ws += (size_t)BATCH * INNERD * 4;         // 8 KiB (contiguous after cm)
  float* weff = (float*)ws; ws += (size_t)BATCH * INNERD * CDIM * 4;  // 2 MiB
  u16* Gt     = (u16*)ws;  ws += (size_t)BATCH * CDIM * CDIM * 2;

  const int nzero = BATCH * 8 * 64 * 64 + BATCH * INNERD;  // cm + ksum

  transpose_cvt<<<dim3(NTOK / 32, CDIM / 64, BATCH * 2), 256, 0, stream>>>(x, ctx, x_bt, ctx_bt);
  wtrans<<<dim3(INNERD / 32, CDIM / 32, 3), 256, 0, stream>>>(Wq, Wk, Wv, Wq_t, Wk_t, Wv_t);
  zero_f32<<<(nzero + 255) / 256, 256, 0, stream>>>(cm, nzero);
  proj_gemm<<<dim3(4096), 256, 0, stream>>>(Wk_t, Wv_t, ctx_bt, ktb, vtb);
  ctx_mat<<<dim3(BATCH * 8, NTOK / CM_CHUNK), 256, 0, stream>>>(ktb, vtb, cm, ksum);
  weff_k<<<BATCH * INNERD, 256, 0, stream>>>(cm, Wo, ksum, weff);
  gt_k<<<BATCH * CDIM, 256, 0, stream>>>(weff, Wq_t, Gt);
  final_gemm<<<dim3(1024), 256, 0, stream>>>(Gt, x_bt, x, bo, out);
}

// Round 4
// 333.346 us; speedup vs baseline: 1.1936x; 1.1106x over previous
//
#include <hip/hip_runtime.h>

typedef unsigned short u16;
typedef u16   u16x4  __attribute__((ext_vector_type(4)));
typedef u16   u16x8  __attribute__((ext_vector_type(8)));
typedef __bf16 bf16x8 __attribute__((ext_vector_type(8)));
typedef float f32x4  __attribute__((ext_vector_type(4)));

constexpr int BATCH  = 4;
constexpr int CDIM   = 256;
constexpr int NTOK   = 16384;   // 128*128
constexpr int INNERD = 512;

// native bf16 converts (v_cvt_pk_bf16_f32, RNE — same rounding as the old bit-twiddle)
__device__ __forceinline__ u16 f2b(float f) {
  return __builtin_bit_cast(u16, (__bf16)f);
}
__device__ __forceinline__ float b2f(u16 b) {
  return (float)__builtin_bit_cast(__bf16, b);
}

// async global->LDS, 16B per lane. LDS dest must be WAVE-UNIFORM base;
// HW writes lane i's data at base + i*16. Global src is per-lane.
__device__ __forceinline__ void async_ld16(const u16* g, u16* l) {
  __builtin_amdgcn_global_load_lds(
      (const __attribute__((address_space(1))) void*)g,
      (__attribute__((address_space(3))) void*)l, 16, 0, 0);
}

// ---------------- transpose + convert: (b,c,n) fp32 -> (b,n,c) bf16 -------------
__global__ __launch_bounds__(256) void transpose_cvt(
    const float* __restrict__ x, const float* __restrict__ ctx,
    u16* __restrict__ xt, u16* __restrict__ ct) {
  __shared__ float tile[64][33];
  int zb = blockIdx.z;            // 0..7 : b*2 + which
  int b = zb >> 1;
  const float* src = (zb & 1) ? ctx : x;
  u16* dst = (zb & 1) ? ct : xt;
  src += (size_t)b * CDIM * NTOK;
  dst += (size_t)b * NTOK * CDIM;
  int n0 = blockIdx.x * 32, c0 = blockIdx.y * 64;
  int tx = threadIdx.x & 31, ty = threadIdx.x >> 5;   // ty 0..7
#pragma unroll
  for (int i = 0; i < 64; i += 8)
    tile[ty + i][tx] = src[(size_t)(c0 + ty + i) * NTOK + n0 + tx];
  __syncthreads();
  int nl = threadIdx.x >> 3;          // 0..31
  int cl = (threadIdx.x & 7) * 8;     // 0..56
  u16x8 o;
#pragma unroll
  for (int j = 0; j < 8; j++) o[j] = f2b(tile[cl + j][nl]);
  *(u16x8*)&dst[(size_t)(n0 + nl) * CDIM + c0 + cl] = o;
}

// ---------------- weight transpose: (256,512) fp32 -> (512,256) bf16 ------------
__global__ __launch_bounds__(256) void wtrans(
    const float* __restrict__ Wq, const float* __restrict__ Wk, const float* __restrict__ Wv,
    u16* __restrict__ qt, u16* __restrict__ kt, u16* __restrict__ vt) {
  __shared__ float tile[32][33];
  const float* src = blockIdx.z == 0 ? Wq : (blockIdx.z == 1 ? Wk : Wv);
  u16* dst = blockIdx.z == 0 ? qt : (blockIdx.z == 1 ? kt : vt);
  int i0 = blockIdx.x * 32, c0 = blockIdx.y * 32;
  int tx = threadIdx.x & 31, ty = threadIdx.x >> 5;
#pragma unroll
  for (int r = 0; r < 32; r += 8)
    tile[ty + r][tx] = src[(size_t)(c0 + ty + r) * INNERD + i0 + tx];
  __syncthreads();
#pragma unroll
  for (int r = 0; r < 32; r += 8)
    dst[(size_t)(i0 + ty + r) * CDIM + c0 + tx] = f2b(tile[tx][ty + r]);
}

// ---------------- zero scratch -------------------------------------------------
__global__ void zero_f32(float* p, int nelem) {
  int i = blockIdx.x * blockDim.x + threadIdx.x;
  if (i < nelem) p[i] = 0.0f;
}

// ================= fused projection + context matrix ===========================
// Per block: b, i-range 128 (heads ig*2, ig*2+1), n-chunk 512.
//   per 128-n tile: K-GEMM -> exp -> Ek(LDS, XOR-swz); V-GEMM (same acc regs)
//   -> Vt(LDS, aliases staging); then cm MFMA: acc_cm[h][d][e] += Ek·Vt^T,
//   ksum via ones-operand. Epilogue: atomics into cm/ksum.
// ktb/vtb (260 MB of HBM round-trip) are eliminated entirely.
__global__ __launch_bounds__(256, 2) void proj_ctx(
    const u16* __restrict__ Wkt, const u16* __restrict__ Wvt,
    const u16* __restrict__ ctx_bt, float* __restrict__ cm, float* __restrict__ ksum) {
  // 512 blocks = 4(ig) x 32(nc) x 4(b); chunked XCD swizzle: XCD gets 64
  // consecutive swz -> ig fastest (4 siblings share the ctx slice in L2).
  int id = blockIdx.x;
  int swz = (id & 7) * 64 + (id >> 3);
  int ig = swz & 3, nc = (swz >> 2) & 31, b = swz >> 7;
  int i0 = ig * 128;
  const u16* Bt = ctx_bt + (size_t)b * NTOK * CDIM;

  __shared__ __align__(16) u16 smem[32768];   // 64 KiB -> 2 blocks/CU
  u16* As = smem;            // [0,16K)   staging A (K or V weights)
  u16* Bs = smem + 8192;     // [16K,32K) staging B (ctx)
  u16* Vt = smem;            // [0,32K)   V tile, aliases staging
  u16* Ek = smem + 16384;    // [32K,64K) expK tile, dedicated

  int tid = threadIdx.x, wave = tid >> 6, lane = tid & 63;
  int wm = (wave >> 1) * 64, wn = (wave & 1) * 64;
  int quad = lane >> 4, l16 = lane & 15;
  int srow = lane >> 3, scol = (lane & 7) * 8;

  int hl = wave >> 1, dblk = (wave & 1) * 32;   // phase-2: wave -> (head, d-half)

  u16x8 ov;
#pragma unroll
  for (int t = 0; t < 8; t++) ov[t] = 0x3f80;   // bf16 1.0
  const bf16x8 ones = __builtin_bit_cast(bf16x8, ov);

  f32x4 acc_cm[2][4];
  f32x4 accS[2];
#pragma unroll
  for (int i = 0; i < 2; i++) {
    accS[i] = (f32x4)(0.0f);
#pragma unroll
    for (int j = 0; j < 4; j++) acc_cm[i][j] = (f32x4)(0.0f);
  }

  for (int nt = 0; nt < 4; nt++) {
    int n0 = nc * 512 + nt * 128;
#pragma unroll 1
    for (int kv = 0; kv < 2; kv++) {
      const u16* A = kv ? Wvt : Wkt;
      f32x4 acc[4][4];
#pragma unroll
      for (int i = 0; i < 4; i++)
#pragma unroll
        for (int j = 0; j < 4; j++) acc[i][j] = (f32x4)(0.0f);

      for (int k0 = 0; k0 < CDIM; k0 += 64) {
        __syncthreads();                 // prev reads of As/Bs (or Vt/cm) done
#pragma unroll
        for (int j = 0; j < 4; j++) {
          int t = wave * 4 + j;          // 0..15
          int row = t * 8 + srow;
          async_ld16(&A [(size_t)(i0 + row) * CDIM + k0 + scol], &As[t * 512]);
          async_ld16(&Bt[(size_t)(n0 + row) * CDIM + k0 + scol], &Bs[t * 512]);
        }
        __syncthreads();                 // drains vmcnt(0)
#pragma unroll
        for (int kk = 0; kk < 64; kk += 32) {
          int ko = kk + quad * 8;
          bf16x8 af[4], bfr[4];
#pragma unroll
          for (int m = 0; m < 4; m++)
            af[m] = __builtin_bit_cast(bf16x8, *(const u16x8*)&As[(wm + m * 16 + l16) * 64 + ko]);
#pragma unroll
          for (int e = 0; e < 4; e++)
            bfr[e] = __builtin_bit_cast(bf16x8, *(const u16x8*)&Bs[(wn + e * 16 + l16) * 64 + ko]);
          // swapped operands: lane holds 4 consecutive n per frag
#pragma unroll
          for (int e = 0; e < 4; e++)
#pragma unroll
            for (int m = 0; m < 4; m++)
              acc[e][m] = __builtin_amdgcn_mfma_f32_16x16x32_bf16(bfr[e], af[m], acc[e][m], 0, 0, 0);
        }
      }
      __syncthreads();                   // all frag reads done (Vt aliases staging)
      // write tile to LDS, XOR-swizzled: byte ^= (row&7)<<4  (2-way max on r/w)
      u16* T = kv ? Vt : Ek;
#pragma unroll
      for (int e = 0; e < 4; e++) {
        int nl0 = wn + e * 16 + quad * 4;
#pragma unroll
        for (int m = 0; m < 4; m++) {
          int row = wm + m * 16 + l16;   // i-local 0..127
          u16x4 o;
#pragma unroll
          for (int r = 0; r < 4; r++) {
            float v = acc[e][m][r];
            if (!kv) v = __expf(v);      // loop-uniform branch
            o[r] = f2b(v);
          }
          unsigned byt = (unsigned)(row * 256 + nl0 * 2) ^ ((unsigned)(row & 7) << 4);
          *(u16x4*)((char*)T + byt) = o;
        }
      }
    }
    __syncthreads();                     // Ek/Vt visible to all waves
    // phase 2: per wave (hl, dblk): acc_cm[m2][e2] += Ek_row · Vt_row over 128 n
#pragma unroll
    for (int kk = 0; kk < 128; kk += 32) {
      int ko = kk + quad * 8;
      bf16x8 ea[2], vb[4];
#pragma unroll
      for (int m2 = 0; m2 < 2; m2++) {
        int row = hl * 64 + dblk + m2 * 16 + l16;
        unsigned byt = (unsigned)(row * 256 + ko * 2) ^ ((unsigned)(row & 7) << 4);
        ea[m2] = __builtin_bit_cast(bf16x8, *(const u16x8*)((char*)Ek + byt));
      }
#pragma unroll
      for (int e2 = 0; e2 < 4; e2++) {
        int row = hl * 64 + e2 * 16 + l16;
        unsigned byt = (unsigned)(row * 256 + ko * 2) ^ ((unsigned)(row & 7) << 4);
        vb[e2] = __builtin_bit_cast(bf16x8, *(const u16x8*)((char*)Vt + byt));
      }
#pragma unroll
      for (int m2 = 0; m2 < 2; m2++) {
        accS[m2] = __builtin_amdgcn_mfma_f32_16x16x32_bf16(ea[m2], ones, accS[m2], 0, 0, 0);
#pragma unroll
        for (int e2 = 0; e2 < 4; e2++)
          acc_cm[m2][e2] = __builtin_amdgcn_mfma_f32_16x16x32_bf16(ea[m2], vb[e2], acc_cm[m2][e2], 0, 0, 0);
      }
    }
    // next nt's first __syncthreads protects Ek/Vt vs staging overwrite
  }
  // epilogue: waves own disjoint (h, d-half) -> no intra-block contention
  int h = ig * 2 + hl;
  float* cmp = cm + (size_t)(b * 8 + h) * 64 * 64;
#pragma unroll
  for (int m2 = 0; m2 < 2; m2++)
#pragma unroll
    for (int e2 = 0; e2 < 4; e2++)
#pragma unroll
      for (int r = 0; r < 4; r++) {
        int d = dblk + m2 * 16 + quad * 4 + r;
        int e = e2 * 16 + l16;
        atomicAdd(&cmp[d * 64 + e], acc_cm[m2][e2][r]);
      }
  if (l16 == 0) {
#pragma unroll
    for (int m2 = 0; m2 < 2; m2++)
#pragma unroll
      for (int r = 0; r < 4; r++) {
        int d = dblk + m2 * 16 + quad * 4 + r;
        atomicAdd(&ksum[(size_t)b * INNERD + h * 64 + d], accS[m2][r]);
      }
  }
}

// ---------------- weff[b][i=h*64+d][c] = (sum_e cm[d][e]*Wo[h*64+e][c])/ksum ---
__global__ __launch_bounds__(256) void weff_k(
    const float* __restrict__ cm, const float* __restrict__ Wo,
    const float* __restrict__ ksum, float* __restrict__ weff) {
  int bi = blockIdx.x;            // 0..2047
  int b = bi >> 9, i = bi & 511, h = i >> 6, d = i & 63;
  const float* cmr = cm + ((size_t)(b * 8 + h) * 64 + d) * 64;
  __shared__ float cs[64];
  if (threadIdx.x < 64) cs[threadIdx.x] = cmr[threadIdx.x];
  __syncthreads();
  float inv = 1.0f / ksum[(size_t)b * INNERD + i];
  int c = threadIdx.x;
  float s = 0.0f;
#pragma unroll 8
  for (int e = 0; e < 64; e++) s += cs[e] * Wo[(size_t)(h * 64 + e) * CDIM + c];
  weff[(size_t)bi * CDIM + c] = s * inv;
}

// ---------------- Gt[b][c][c'] = sum_i weff[b][i][c] * Wq_t[i][c']  (bf16) -----
__global__ __launch_bounds__(256) void gt_k(
    const float* __restrict__ weff, const u16* __restrict__ Wq_t, u16* __restrict__ Gt) {
  int bc = blockIdx.x;            // 0..1023
  int b = bc >> 8, c = bc & 255;
  __shared__ float ws[512];
  for (int j = threadIdx.x; j < 512; j += 256)
    ws[j] = weff[((size_t)b * 512 + j) * CDIM + c];
  __syncthreads();
  int cp = threadIdx.x;
  float s = 0.0f;
#pragma unroll 8
  for (int i = 0; i < 512; i++) s += ws[i] * b2f(Wq_t[(size_t)i * CDIM + cp]);
  Gt[(size_t)bc * CDIM + cp] = f2b(s);
}

// ---------------- final: out[b][c][n] = x + bo[c] + sum_c' Gt[c][c'] x_bt[n][c']
// SWAPPED operands: lane holds 4 consecutive n -> float4 load of x, float4 store.
__global__ __launch_bounds__(256) void final_gemm(
    const u16* __restrict__ Gt, const u16* __restrict__ x_bt,
    const float* __restrict__ x, const float* __restrict__ bo,
    float* __restrict__ out) {
  // flattened grid 1024 = 2(x) * 128(y) * 4(z); chunked XCD swizzle
  int id = blockIdx.x;
  int swz = (id & 7) * 128 + (id >> 3);
  int bx = swz & 1, by = (swz >> 1) & 127, b = swz >> 8;
  const u16* A  = Gt + (size_t)b * CDIM * CDIM;
  const u16* Bt = x_bt + (size_t)b * NTOK * CDIM;
  const float* xb = x + (size_t)b * CDIM * NTOK;
  float* ob = out + (size_t)b * CDIM * NTOK;
  int i0 = bx * 128;
  int n0 = by * 128;

  __shared__ __align__(16) u16 As[128 * 64];
  __shared__ __align__(16) u16 Bs[128 * 64];

  int tid = threadIdx.x;
  int wave = tid >> 6, lane = tid & 63;
  int wm = (wave >> 1) * 64, wn = (wave & 1) * 64;
  int quad = lane >> 4, l16 = lane & 15;
  int srow = lane >> 3, scol = (lane & 7) * 8;

  f32x4 acc[4][4];   // [e:n-frag][m:c-frag]
#pragma unroll
  for (int i = 0; i < 4; i++)
#pragma unroll
    for (int j = 0; j < 4; j++) acc[i][j] = (f32x4)(0.0f);

  for (int k0 = 0; k0 < CDIM; k0 += 64) {
    __syncthreads();
#pragma unroll
    for (int j = 0; j < 4; j++) {
      int t = wave * 4 + j;
      int row = t * 8 + srow;
      async_ld16(&A [(size_t)(i0 + row) * CDIM + k0 + scol], &As[t * 512]);
      async_ld16(&Bt[(size_t)(n0 + row) * CDIM + k0 + scol], &Bs[t * 512]);
    }
    __syncthreads();
#pragma unroll
    for (int kk = 0; kk < 64; kk += 32) {
      int ko = kk + quad * 8;
      bf16x8 af[4], bfr[4];
#pragma unroll
      for (int m = 0; m < 4; m++)
        af[m] = __builtin_bit_cast(bf16x8, *(const u16x8*)&As[(wm + m * 16 + l16) * 64 + ko]);
#pragma unroll
      for (int e = 0; e < 4; e++)
        bfr[e] = __builtin_bit_cast(bf16x8, *(const u16x8*)&Bs[(wn + e * 16 + l16) * 64 + ko]);
#pragma unroll
      for (int e = 0; e < 4; e++)
#pragma unroll
        for (int m = 0; m < 4; m++)
          acc[e][m] = __builtin_amdgcn_mfma_f32_16x16x32_bf16(bfr[e], af[m], acc[e][m], 0, 0, 0);
    }
  }
  // lane's acc[e][m][r]: c = i0+wm+m*16+l16, n = n0+wn+e*16+quad*4+r
#pragma unroll
  for (int e = 0; e < 4; e++) {
    int nb = n0 + wn + e * 16 + quad * 4;
#pragma unroll
    for (int m = 0; m < 4; m++) {
      int c = i0 + wm + m * 16 + l16;
      f32x4 xv = *(const f32x4*)&xb[(size_t)c * NTOK + nb];
      f32x4 r;
      float bc = bo[c];
#pragma unroll
      for (int t = 0; t < 4; t++) r[t] = acc[e][m][t] + xv[t] + bc;
      *(f32x4*)&ob[(size_t)c * NTOK + nb] = r;
    }
  }
}

extern "C" void kernel_launch(void* const* d_in, const int* in_sizes, int n_in,
                              void* d_out, int out_size, void* d_ws, size_t ws_size,
                              hipStream_t stream) {
  const float* x   = (const float*)d_in[0];
  const float* ctx = (const float*)d_in[1];
  const float* Wq  = (const float*)d_in[2];
  const float* Wk  = (const float*)d_in[3];
  const float* Wv  = (const float*)d_in[4];
  const float* Wo  = (const float*)d_in[5];
  const float* bo  = (const float*)d_in[6];
  float* out = (float*)d_out;

  char* ws = (char*)d_ws;
  u16* ctx_bt = (u16*)ws;  ws += (size_t)BATCH * NTOK * CDIM * 2;     // 32 MiB
  u16* x_bt   = (u16*)ws;  ws += (size_t)BATCH * NTOK * CDIM * 2;     // 32 MiB
  u16* Wq_t   = (u16*)ws;  ws += (size_t)INNERD * CDIM * 2;
  u16* Wk_t   = (u16*)ws;  ws += (size_t)INNERD * CDIM * 2;
  u16* Wv_t   = (u16*)ws;  ws += (size_t)INNERD * CDIM * 2;
  float* cm   = (float*)ws; ws += (size_t)BATCH * 8 * 64 * 64 * 4;    // 512 KiB
  float* ksum = (float*)ws; ws += (size_t)BATCH * INNERD * 4;         // 8 KiB (contiguous after cm)
  float* weff = (float*)ws; ws += (size_t)BATCH * INNERD * CDIM * 4;  // 2 MiB
  u16* Gt     = (u16*)ws;  ws += (size_t)BATCH * CDIM * CDIM * 2;

  const int nzero = BATCH * 8 * 64 * 64 + BATCH * INNERD;  // cm + ksum

  transpose_cvt<<<dim3(NTOK / 32, CDIM / 64, BATCH * 2), 256, 0, stream>>>(x, ctx, x_bt, ctx_bt);
  wtrans<<<dim3(INNERD / 32, CDIM / 32, 3), 256, 0, stream>>>(Wq, Wk, Wv, Wq_t, Wk_t, Wv_t);
  zero_f32<<<(nzero + 255) / 256, 256, 0, stream>>>(cm, nzero);
  proj_ctx<<<dim3(512), 256, 0, stream>>>(Wk_t, Wv_t, ctx_bt, cm, ksum);
  weff_k<<<BATCH * INNERD, 256, 0, stream>>>(cm, Wo, ksum, weff);
  gt_k<<<BATCH * CDIM, 256, 0, stream>>>(weff, Wq_t, Gt);
  final_gemm<<<dim3(1024), 256, 0, stream>>>(Gt, x_bt, x, bo, out);
}